// Round 1
// 1266.880 us; speedup vs baseline: 1.1374x; 1.1374x over previous
//
#include <hip/hip_runtime.h>
#include <hip/hip_bf16.h>
#include <cstdint>
#include <cstddef>

// WindowAttention (B=4096, N=49, C=384, H=12, D=32), fp32 I/O, bf16 MFMA compute.
// Pipeline: cvt(fp32->bf16) -> qkv GEMM (+bias,+scale,+layout) -> per-head attention -> proj GEMM.
// MFMA 16x16x32 bf16 layouts (HW-verified per guide):
//   A[m=lane&15][k=quad*8+j], B[k=quad*8+j][n=lane&15],
//   C/D: col=lane&15, row=quad*4+reg.
//
// Round-1 changes vs previous version:
//  - qkv/proj mainloop: global_load_lds dwordx4 staging, double-buffered LDS,
//    XOR-swizzled chunks (pre-swizzled global src, swizzled ds_read -> 2-way max
//    bank aliasing, free), counted s_waitcnt vmcnt(4) so next tile's loads stay
//    in flight across the barrier.
//  - attn: mask folded into MFMA accumulator init with coalesced loads
//    (replaces 2x49 per-lane strided fp32 loads in softmax); blocks regrouped so
//    4 waves share one batch b (mask L1-hot).

typedef __bf16 bf16_t;
typedef __bf16 bf16x8 __attribute__((ext_vector_type(8)));
typedef __bf16 bf16x4 __attribute__((ext_vector_type(4)));
typedef float  floatx4 __attribute__((ext_vector_type(4)));

#define MFMA16(a, b, c) __builtin_amdgcn_mfma_f32_16x16x32_bf16((a), (b), (c), 0, 0, 0)

static const int CH   = 384;      // channels
static const int MTOT = 200704;   // 4096*49 rows

__device__ __forceinline__ void gload16(const bf16_t* g, bf16_t* l) {
    // async global->LDS, 16B per lane; LDS dest = wave-uniform base + lane*16
    __builtin_amdgcn_global_load_lds(
        (const __attribute__((address_space(1))) unsigned int*)g,
        (__attribute__((address_space(3))) unsigned int*)l,
        16, 0, 0);
}

// ---------------- fp32 -> bf16 convert, 4 elems/thread, exact grid ----------------
__global__ void cvt_kernel(const float* __restrict__ src, bf16_t* __restrict__ dst) {
    int i = (blockIdx.x * 256 + threadIdx.x) * 4;
    float4 v = *(const float4*)(src + i);
    bf16x4 o;
    o[0] = (bf16_t)v.x; o[1] = (bf16_t)v.y; o[2] = (bf16_t)v.z; o[3] = (bf16_t)v.w;
    *(bf16x4*)(dst + i) = o;
}

// ---------------- QKV GEMM: [200704,384] @ [1152,384]^T, 128x128 tile, BK=32 ----------------
// LDS tile: linear [128][4 chunks of 16B]; chunk position p holds global chunk
// p ^ ((row>>1)&3) (source pre-swizzle); reader XORs the same way. 2-way bank alias max.
__global__ __launch_bounds__(256) void qkv_kernel(
    const bf16_t* __restrict__ xb, const bf16_t* __restrict__ wb,
    const float* __restrict__ bias,
    bf16_t* __restrict__ qb, bf16_t* __restrict__ kb, bf16_t* __restrict__ vb)
{
    __shared__ __align__(16) bf16_t As[2][128 * 32];
    __shared__ __align__(16) bf16_t Bs[2][128 * 32];
    const int tid  = threadIdx.x;
    const int lane = tid & 63, wave = tid >> 6;
    const int quad = lane >> 4, l15 = lane & 15;
    const int m0 = blockIdx.x * 128, j0 = blockIdx.y * 128;
    const int wrow = (wave & 1) * 64, wcol = (wave >> 1) * 64;

    floatx4 acc[4][4];
#pragma unroll
    for (int a = 0; a < 4; ++a)
#pragma unroll
        for (int b2 = 0; b2 < 4; ++b2)
#pragma unroll
            for (int r = 0; r < 4; ++r) acc[a][b2][r] = 0.f;

#define QKV_STAGE(KT, BI)                                                          \
    do {                                                                           \
        const int k0s = (KT) * 32;                                                 \
        _Pragma("unroll")                                                          \
        for (int rd = 0; rd < 2; ++rd) {                                           \
            int c = rd * 256 + tid;                                                \
            int row = c >> 2, p = c & 3;                                           \
            int q = p ^ ((row >> 1) & 3);                                          \
            gload16(xb + (size_t)(m0 + row) * CH + k0s + q * 8, &As[BI][c * 8]);   \
            gload16(wb + (size_t)(j0 + row) * CH + k0s + q * 8, &Bs[BI][c * 8]);   \
        }                                                                          \
    } while (0)

    QKV_STAGE(0, 0);
#pragma unroll
    for (int kt = 0; kt < 12; ++kt) {
        const int cur = kt & 1;
        if (kt < 11) {
            QKV_STAGE(kt + 1, cur ^ 1);
            asm volatile("s_waitcnt vmcnt(4)" ::: "memory");
        } else {
            asm volatile("s_waitcnt vmcnt(0)" ::: "memory");
        }
        __builtin_amdgcn_sched_barrier(0);
        __builtin_amdgcn_s_barrier();
        bf16x8 af[4], bfr[4];
#pragma unroll
        for (int mt = 0; mt < 4; ++mt) {
            int rA = wrow + mt * 16 + l15;
            af[mt]  = *(const bf16x8*)&As[cur][rA * 32 + (quad ^ ((rA >> 1) & 3)) * 8];
            int rB = wcol + mt * 16 + l15;
            bfr[mt] = *(const bf16x8*)&Bs[cur][rB * 32 + (quad ^ ((rB >> 1) & 3)) * 8];
        }
#pragma unroll
        for (int mt = 0; mt < 4; ++mt)
#pragma unroll
            for (int nt = 0; nt < 4; ++nt)
                acc[mt][nt] = MFMA16(af[mt], bfr[nt], acc[mt][nt]);
        asm volatile("s_waitcnt lgkmcnt(0)" ::: "memory");
        __builtin_amdgcn_sched_barrier(0);
        __builtin_amdgcn_s_barrier();
    }
#undef QKV_STAGE

    const int t = j0 / CH;  // 0=q 1=k 2=v; uniform per block (384 = 3*128)
#pragma unroll
    for (int mt = 0; mt < 4; ++mt)
#pragma unroll
        for (int r = 0; r < 4; ++r) {
            unsigned m = (unsigned)(m0 + wrow + mt * 16 + quad * 4 + r);
            unsigned b = m / 49u, n = m % 49u;
#pragma unroll
            for (int nt = 0; nt < 4; ++nt) {
                unsigned j = (unsigned)(j0 + wcol + nt * 16 + l15);
                float val = acc[mt][nt][r] + bias[j];
                unsigned jr = j - (unsigned)(t * CH);
                unsigned h = jr >> 5, d = jr & 31u;
                size_t bh = (size_t)b * 12u + h;
                if (t == 0)      qb[(bh * 49u + n) * 32u + d] = (bf16_t)(val * 0.17677669529663687f);
                else if (t == 1) kb[(bh * 49u + n) * 32u + d] = (bf16_t)val;
                else             vb[(bh * 32u + d) * 64u + n] = (bf16_t)val;  // v transposed, padded to 64
            }
        }
}

// ---------------- attention: one wave per (b,h); 4 waves/block share one b ----------------
__global__ __launch_bounds__(256) void attn_kernel(
    const bf16_t* __restrict__ qb, const bf16_t* __restrict__ kb,
    const bf16_t* __restrict__ vb, const float* __restrict__ mask,
    bf16_t* __restrict__ ao)
{
    __shared__ __align__(16) bf16_t S[4][64][72];  // per-wave 64x64 logits/P, +8 pad
    __shared__ float rsum[4][64];                  // per-row 1/sum
    const int tid  = threadIdx.x;
    const int w = tid >> 6, lane = tid & 63;
    const int quad = lane >> 4, l15 = lane & 15;
    const unsigned b = blockIdx.x / 3u;                       // uniform per block
    const unsigned h = (blockIdx.x % 3u) * 4u + (unsigned)w;  // 4 heads per block
    const unsigned gw = b * 12u + h;
    const bf16_t* qh = qb + (size_t)gw * 1568u;  // 49*32
    const bf16_t* kh = kb + (size_t)gw * 1568u;
    const bf16_t* vh = vb + (size_t)gw * 2048u;  // 32*64
    const float*  mb = mask + (size_t)b * 2401u; // 49*49

    // S = q @ k^T + mask (scale already folded into q; mask folded into acc init)
    bf16x8 qf[4], kf[4];
#pragma unroll
    for (int mt = 0; mt < 4; ++mt) qf[mt] = *(const bf16x8*)&qh[(mt * 16 + l15) * 32 + quad * 8];
#pragma unroll
    for (int nt = 0; nt < 4; ++nt) kf[nt] = *(const bf16x8*)&kh[(nt * 16 + l15) * 32 + quad * 8];
    floatx4 sacc[4][4];
    // init accumulator with mask: C/D layout is col=l15, row=quad*4+r -> coalesced 64B loads
#pragma unroll
    for (int mt = 0; mt < 4; ++mt)
#pragma unroll
        for (int r = 0; r < 4; ++r) {
            int rr = mt * 16 + quad * 4 + r;
            const float* mrow = mb + rr * 49;
#pragma unroll
            for (int nt = 0; nt < 4; ++nt) {
                int col = nt * 16 + l15;
                float mval = 0.f;
                if (rr < 49) mval = mrow[col < 49 ? col : 48];  // clamp: cols>=49 unused
                sacc[mt][nt][r] = mval;
            }
        }
#pragma unroll
    for (int mt = 0; mt < 4; ++mt)
#pragma unroll
        for (int nt = 0; nt < 4; ++nt)
            sacc[mt][nt] = MFMA16(qf[mt], kf[nt], sacc[mt][nt]);

    // C-layout -> LDS (masked logits, bf16)
#pragma unroll
    for (int mt = 0; mt < 4; ++mt)
#pragma unroll
        for (int nt = 0; nt < 4; ++nt)
#pragma unroll
            for (int r = 0; r < 4; ++r)
                S[w][mt * 16 + quad * 4 + r][nt * 16 + l15] = (bf16_t)sacc[mt][nt][r];
    __syncthreads();

    // per-row softmax (lane r owns row r), P stored unnormalized; mask already in S
    const int r = lane;
    if (r < 49) {
        float mx = -1e30f;
#pragma unroll
        for (int ch = 0; ch < 7; ++ch) {
            bf16x8 v = *(const bf16x8*)&S[w][r][ch * 8];
#pragma unroll
            for (int jj = 0; jj < 8; ++jj) {
                int c = ch * 8 + jj;
                if (c < 49) mx = fmaxf(mx, (float)v[jj]);
            }
        }
        float sum = 0.f;
#pragma unroll
        for (int ch = 0; ch < 7; ++ch) {
            bf16x8 v = *(const bf16x8*)&S[w][r][ch * 8];
            bf16x8 pv;
#pragma unroll
            for (int jj = 0; jj < 8; ++jj) {
                int c = ch * 8 + jj;
                float p = 0.f;
                if (c < 49) { p = __expf((float)v[jj] - mx); sum += p; }
                pv[jj] = (bf16_t)p;
            }
            *(bf16x8*)&S[w][r][ch * 8] = pv;
        }
        bf16x8 z;
#pragma unroll
        for (int jj = 0; jj < 8; ++jj) z[jj] = (bf16_t)0.f;
        *(bf16x8*)&S[w][r][56] = z;  // cols 56..63 = 0 (49..55 zeroed above)
        rsum[w][r] = 1.f / sum;
    }
    __syncthreads();

    // O = P @ V  (v stored transposed [32][64])
    floatx4 oacc[4][2];
#pragma unroll
    for (int a = 0; a < 4; ++a)
#pragma unroll
        for (int c = 0; c < 2; ++c)
#pragma unroll
            for (int rr = 0; rr < 4; ++rr) oacc[a][c][rr] = 0.f;
#pragma unroll
    for (int kt = 0; kt < 2; ++kt) {
        bf16x8 pf[4], vf[2];
#pragma unroll
        for (int mt = 0; mt < 4; ++mt) pf[mt] = *(const bf16x8*)&S[w][mt * 16 + l15][kt * 32 + quad * 8];
#pragma unroll
        for (int nt = 0; nt < 2; ++nt) vf[nt] = *(const bf16x8*)&vh[(nt * 16 + l15) * 64 + kt * 32 + quad * 8];
#pragma unroll
        for (int mt = 0; mt < 4; ++mt)
#pragma unroll
            for (int nt = 0; nt < 2; ++nt)
                oacc[mt][nt] = MFMA16(pf[mt], vf[nt], oacc[mt][nt]);
    }
    // epilogue: normalize by rowsum, write [b, n, h*32+d] bf16
#pragma unroll
    for (int mt = 0; mt < 4; ++mt)
#pragma unroll
        for (int nt = 0; nt < 2; ++nt)
#pragma unroll
            for (int rr = 0; rr < 4; ++rr) {
                int row = mt * 16 + quad * 4 + rr;
                if (row < 49) {
                    float val = oacc[mt][nt][rr] * rsum[w][row];
                    ao[((size_t)b * 49u + (unsigned)row) * 384u + h * 32u + (unsigned)(nt * 16 + l15)] = (bf16_t)val;
                }
            }
}

// ---------------- proj GEMM: [200704,384] @ [384,384]^T + bias -> fp32 out ----------------
__global__ __launch_bounds__(256) void proj_kernel(
    const bf16_t* __restrict__ ab, const bf16_t* __restrict__ wb,
    const float* __restrict__ bias, float* __restrict__ out)
{
    __shared__ __align__(16) bf16_t As[2][128 * 32];
    __shared__ __align__(16) bf16_t Bs[2][128 * 32];
    const int tid  = threadIdx.x;
    const int lane = tid & 63, wave = tid >> 6;
    const int quad = lane >> 4, l15 = lane & 15;
    const int m0 = blockIdx.x * 128, j0 = blockIdx.y * 128;
    const int wrow = (wave & 1) * 64, wcol = (wave >> 1) * 64;

    floatx4 acc[4][4];
#pragma unroll
    for (int a = 0; a < 4; ++a)
#pragma unroll
        for (int b2 = 0; b2 < 4; ++b2)
#pragma unroll
            for (int r = 0; r < 4; ++r) acc[a][b2][r] = 0.f;

#define PROJ_STAGE(KT, BI)                                                         \
    do {                                                                           \
        const int k0s = (KT) * 32;                                                 \
        _Pragma("unroll")                                                          \
        for (int rd = 0; rd < 2; ++rd) {                                           \
            int c = rd * 256 + tid;                                                \
            int row = c >> 2, p = c & 3;                                           \
            int q = p ^ ((row >> 1) & 3);                                          \
            gload16(ab + (size_t)(m0 + row) * CH + k0s + q * 8, &As[BI][c * 8]);   \
            gload16(wb + (size_t)(j0 + row) * CH + k0s + q * 8, &Bs[BI][c * 8]);   \
        }                                                                          \
    } while (0)

    PROJ_STAGE(0, 0);
#pragma unroll
    for (int kt = 0; kt < 12; ++kt) {
        const int cur = kt & 1;
        if (kt < 11) {
            PROJ_STAGE(kt + 1, cur ^ 1);
            asm volatile("s_waitcnt vmcnt(4)" ::: "memory");
        } else {
            asm volatile("s_waitcnt vmcnt(0)" ::: "memory");
        }
        __builtin_amdgcn_sched_barrier(0);
        __builtin_amdgcn_s_barrier();
        bf16x8 af[4], bfr[4];
#pragma unroll
        for (int mt = 0; mt < 4; ++mt) {
            int rA = wrow + mt * 16 + l15;
            af[mt]  = *(const bf16x8*)&As[cur][rA * 32 + (quad ^ ((rA >> 1) & 3)) * 8];
            int rB = wcol + mt * 16 + l15;
            bfr[mt] = *(const bf16x8*)&Bs[cur][rB * 32 + (quad ^ ((rB >> 1) & 3)) * 8];
        }
#pragma unroll
        for (int mt = 0; mt < 4; ++mt)
#pragma unroll
            for (int nt = 0; nt < 4; ++nt)
                acc[mt][nt] = MFMA16(af[mt], bfr[nt], acc[mt][nt]);
        asm volatile("s_waitcnt lgkmcnt(0)" ::: "memory");
        __builtin_amdgcn_sched_barrier(0);
        __builtin_amdgcn_s_barrier();
    }
#undef PROJ_STAGE

#pragma unroll
    for (int mt = 0; mt < 4; ++mt)
#pragma unroll
        for (int nt = 0; nt < 4; ++nt)
#pragma unroll
            for (int r = 0; r < 4; ++r) {
                int m = m0 + wrow + mt * 16 + quad * 4 + r;
                int j = j0 + wcol + nt * 16 + l15;
                out[(size_t)m * CH + j] = acc[mt][nt][r] + bias[j];
            }
}

extern "C" void kernel_launch(void* const* d_in, const int* in_sizes, int n_in,
                              void* d_out, int out_size, void* d_ws, size_t ws_size,
                              hipStream_t stream) {
    const float* x      = (const float*)d_in[0];
    const float* mask   = (const float*)d_in[1];
    const float* qkv_w  = (const float*)d_in[2];
    const float* qkv_b  = (const float*)d_in[3];
    const float* proj_w = (const float*)d_in[4];
    const float* proj_b = (const float*)d_in[5];
    float* out = (float*)d_out;

    // workspace layout (bytes)
    const size_t XB_B    = (size_t)77070336 * 2;   // x bf16   (aliased by attn output later)
    const size_t QB_B    = (size_t)77070336 * 2;   // q [b,h,49,32]
    const size_t KB_B    = (size_t)77070336 * 2;   // k [b,h,49,32]
    const size_t VB_B    = (size_t)100663296 * 2;  // v^T [b,h,32,64] padded
    const size_t WQKV_B  = (size_t)442368 * 2;
    const size_t WPROJ_B = (size_t)147456 * 2;
    const size_t NEED = XB_B + QB_B + KB_B + VB_B + WQKV_B + WPROJ_B + 4096;
    if (ws_size < NEED) return;  // fail loudly (poison output) rather than scribble OOB

    char* p = (char*)d_ws;
    bf16_t* xb     = (bf16_t*)p; p += XB_B;   // doubles as attn-output [b,n,384] after qkv reads finish
    bf16_t* qb     = (bf16_t*)p; p += QB_B;
    bf16_t* kb     = (bf16_t*)p; p += KB_B;
    bf16_t* vb     = (bf16_t*)p; p += VB_B;
    bf16_t* wqkvb  = (bf16_t*)p; p += WQKV_B;
    bf16_t* wprojb = (bf16_t*)p;

    cvt_kernel<<<75264, 256, 0, stream>>>(x, xb);          // 77070336/1024
    cvt_kernel<<<432, 256, 0, stream>>>(qkv_w, wqkvb);     // 442368/1024
    cvt_kernel<<<144, 256, 0, stream>>>(proj_w, wprojb);   // 147456/1024
    qkv_kernel<<<dim3(1568, 9), 256, 0, stream>>>(xb, wqkvb, qkv_b, qb, kb, vb);
    attn_kernel<<<12288, 256, 0, stream>>>(qb, kb, vb, mask, xb /*attn out, aliases dead xb*/);
    proj_kernel<<<dim3(1568, 3), 256, 0, stream>>>(xb, wprojb, proj_b, out);
}